// Round 3
// baseline (190.828 us; speedup 1.0000x reference)
//
#include <hip/hip_runtime.h>
#include <hip/hip_cooperative_groups.h>

namespace cg = cooperative_groups;

// Problem constants
#define B_       128
#define N_WAY    5
#define QUERY    15
#define NUM_SLOT 32
#define H_       256
#define NS       (B_ * N_WAY)            // 640 support samples
#define NQ       (B_ * N_WAY * QUERY)    // 9600 query samples
#define ROW      (NUM_SLOT * H_)         // 8192 floats per sample
#define SPB      (N_WAY * QUERY)         // 75 query samples per batch

#define GRID     512                     // co-resident: __launch_bounds__(256,4) -> >=1024 capacity
#define WPG      (GRID * 4)              // 2048 waves

__device__ __forceinline__ float wave_reduce(float v) {
    for (int m = 32; m > 0; m >>= 1) v += __shfl_xor(v, m, 64);
    return v;
}

// Single cooperative kernel: P1 scores -> P2 select -> P3 main -> P4 reduce
__global__ __launch_bounds__(256, 4)
void k_all(const float* __restrict__ out_f, const int* __restrict__ labels_q,
           const float* __restrict__ att_loss, float* __restrict__ ws,
           float* __restrict__ out) {
    cg::grid_group grid = cg::this_grid();
    int wid = threadIdx.x >> 6, lane = threadIdx.x & 63;
    int gw = blockIdx.x * 4 + wid;

    float* scores = ws;                      // 20480
    int*   sel    = (int*)(ws + 20480);      // 640
    float* nllv   = ws + 21120;              // 9600
    float* corrv  = ws + 30720;              // 9600

    __shared__ float sa[256], sb[256];

    // ---- P1: scores[row] = mean over H, one wave per row ----
    for (int row = gw; row < NS * NUM_SLOT; row += WPG) {
        float4 v = ((const float4*)(out_f + (size_t)row * H_))[lane];
        float s = wave_reduce(v.x + v.y + v.z + v.w);
        if (lane == 0) scores[row] = s * (1.0f / H_);
    }
    grid.sync();

    // ---- P2: greedy select, one thread per batch (block 0) ----
    if (blockIdx.x == 0 && threadIdx.x < B_) {
        int b = threadIdx.x;
        const float* sc = scores + (size_t)b * N_WAY * NUM_SLOT;
        unsigned used = 0u;
        for (int j = 0; j < N_WAY; ++j) {
            float best = -INFINITY; int bi = 0;
            #pragma unroll
            for (int s = 0; s < NUM_SLOT; ++s) {
                bool ok = !((used >> s) & 1u);
                float v = sc[j * NUM_SLOT + s];
                if (ok && v > best) { best = v; bi = s; }  // strict > == stable argsort pick
            }
            used |= 1u << bi;
            sel[b * N_WAY + j] = bi;
        }
    }
    grid.sync();

    // ---- P3: per query-sample wave; joint reduce (|q|^2, q.p_raw, |p_raw|^2) ----
    for (int id = gw; id < NQ; id += WPG) {
        int b = id / SPB;
        const float* qrow = out_f + (size_t)(NS + id) * ROW;
        float diffs[N_WAY];
        #pragma unroll
        for (int k = 0; k < N_WAY; ++k) {
            int slot = sel[b * N_WAY + k];
            const float* prow = out_f + (size_t)(b * N_WAY + k) * ROW + (size_t)slot * H_;
            float4 qv = ((const float4*)(qrow + (size_t)slot * H_))[lane];
            float4 pv = ((const float4*)prow)[lane];
            float s2 = qv.x*qv.x + qv.y*qv.y + qv.z*qv.z + qv.w*qv.w;
            float dt = qv.x*pv.x + qv.y*pv.y + qv.z*pv.z + qv.w*pv.w;
            float p2 = pv.x*pv.x + pv.y*pv.y + pv.z*pv.z + pv.w*pv.w;
            for (int m = 32; m > 0; m >>= 1) {
                s2 += __shfl_xor(s2, m, 64);
                dt += __shfl_xor(dt, m, 64);
                p2 += __shfl_xor(p2, m, 64);
            }
            float invq = 1.0f / fmaxf(sqrtf(s2), 1e-12f);
            float invp = 1.0f / fmaxf(sqrtf(p2), 1e-12f);
            diffs[k] = s2 * invq * invq - 2.0f * dt * invq * invp + p2 * invp * invp;
        }
        if (lane == 0) {
            int l = labels_q[id];                    // label index == flat sample index
            float mn = diffs[0]; int am = 0;
            #pragma unroll
            for (int k = 1; k < N_WAY; ++k)
                if (diffs[k] < mn) { mn = diffs[k]; am = k; }  // first min == argmax logits
            float se = 0.0f;
            #pragma unroll
            for (int k = 0; k < N_WAY; ++k) se += expf(mn - diffs[k]);
            nllv[id]  = diffs[l] - mn + logf(se);
            corrv[id] = (am == l) ? 1.0f : 0.0f;
        }
    }
    grid.sync();

    // ---- P4: deterministic fixed-order reduce (block 0) ----
    if (blockIdx.x == 0) {
        int t = threadIdx.x;
        float a = 0.0f, c = 0.0f;
        for (int i = t; i < NQ; i += 256) { a += nllv[i]; c += corrv[i]; }
        sa[t] = a; sb[t] = c;
        __syncthreads();
        for (int off = 128; off > 0; off >>= 1) {
            if (t < off) { sa[t] += sa[t + off]; sb[t] += sb[t + off]; }
            __syncthreads();
        }
        if (t == 0) {
            out[0] = sa[0] * (1.0f / NQ) + att_loss[0];   // LAMBDA = 1.0
            out[1] = sb[0] * (1.0f / NQ);
        }
    }
}

// ---------------- Fallback path (round-1 verified kernels, no atomics) ----------------
__global__ void k_scores(const float* __restrict__ out_f, float* __restrict__ scores) {
    int wid = threadIdx.x >> 6, lane = threadIdx.x & 63;
    int row = blockIdx.x * 4 + wid;
    const float4* p = (const float4*)(out_f + (size_t)row * H_);
    float4 v = p[lane];
    float s = wave_reduce(v.x + v.y + v.z + v.w);
    if (lane == 0) scores[row] = s * (1.0f / H_);
}

__global__ void k_select(const float* __restrict__ scores, int* __restrict__ sel) {
    int b = blockIdx.x * blockDim.x + threadIdx.x;
    if (b >= B_) return;
    const float* sc = scores + (size_t)b * N_WAY * NUM_SLOT;
    unsigned used = 0u;
    for (int j = 0; j < N_WAY; ++j) {
        float best = -INFINITY; int bi = 0;
        for (int s = 0; s < NUM_SLOT; ++s) {
            if (!((used >> s) & 1u)) {
                float v = sc[j * NUM_SLOT + s];
                if (v > best) { best = v; bi = s; }
            }
        }
        used |= 1u << bi;
        sel[b * N_WAY + j] = bi;
    }
}

__global__ void k_main_fb(const float* __restrict__ out_f, const int* __restrict__ sel,
                          const int* __restrict__ labels_q,
                          float* __restrict__ nll, float* __restrict__ corr) {
    int wid = threadIdx.x >> 6, lane = threadIdx.x & 63;
    int id = blockIdx.x * 4 + wid;
    int b = id / SPB;
    const float* qrow = out_f + (size_t)(NS + id) * ROW;
    float diffs[N_WAY];
    #pragma unroll
    for (int k = 0; k < N_WAY; ++k) {
        int slot = sel[b * N_WAY + k];
        const float* prow = out_f + (size_t)(b * N_WAY + k) * ROW + (size_t)slot * H_;
        float4 qv = ((const float4*)(qrow + (size_t)slot * H_))[lane];
        float4 pv = ((const float4*)prow)[lane];
        float s2 = qv.x*qv.x + qv.y*qv.y + qv.z*qv.z + qv.w*qv.w;
        float dt = qv.x*pv.x + qv.y*pv.y + qv.z*pv.z + qv.w*pv.w;
        float p2 = pv.x*pv.x + pv.y*pv.y + pv.z*pv.z + pv.w*pv.w;
        for (int m = 32; m > 0; m >>= 1) {
            s2 += __shfl_xor(s2, m, 64);
            dt += __shfl_xor(dt, m, 64);
            p2 += __shfl_xor(p2, m, 64);
        }
        float invq = 1.0f / fmaxf(sqrtf(s2), 1e-12f);
        float invp = 1.0f / fmaxf(sqrtf(p2), 1e-12f);
        diffs[k] = s2 * invq * invq - 2.0f * dt * invq * invp + p2 * invp * invp;
    }
    if (lane == 0) {
        int l = labels_q[id];
        float mn = diffs[0]; int am = 0;
        #pragma unroll
        for (int k = 1; k < N_WAY; ++k)
            if (diffs[k] < mn) { mn = diffs[k]; am = k; }
        float se = 0.0f;
        #pragma unroll
        for (int k = 0; k < N_WAY; ++k) se += expf(mn - diffs[k]);
        nll[id]  = diffs[l] - mn + logf(se);
        corr[id] = (am == l) ? 1.0f : 0.0f;
    }
}

__global__ void k_finalize(const float* __restrict__ nll, const float* __restrict__ corr,
                           const float* __restrict__ att_loss, float* __restrict__ out) {
    __shared__ float sa[256], sb[256];
    int t = threadIdx.x;
    float a = 0.0f, c = 0.0f;
    for (int i = t; i < NQ; i += 256) { a += nll[i]; c += corr[i]; }
    sa[t] = a; sb[t] = c;
    __syncthreads();
    for (int off = 128; off > 0; off >>= 1) {
        if (t < off) { sa[t] += sa[t + off]; sb[t] += sb[t + off]; }
        __syncthreads();
    }
    if (t == 0) {
        out[0] = sa[0] * (1.0f / NQ) + att_loss[0];
        out[1] = sb[0] * (1.0f / NQ);
    }
}

extern "C" void kernel_launch(void* const* d_in, const int* in_sizes, int n_in,
                              void* d_out, int out_size, void* d_ws, size_t ws_size,
                              hipStream_t stream) {
    const float* out_f    = (const float*)d_in[0];
    // d_in[1] = labels_support (unused by reference)
    const int*   labels_q = (const int*)d_in[2];
    const float* att_loss = (const float*)d_in[3];
    // d_in[4] = mode (unused)
    float* out = (float*)d_out;
    float* ws  = (float*)d_ws;

    void* args[] = { (void*)&out_f, (void*)&labels_q, (void*)&att_loss,
                     (void*)&ws, (void*)&out };
    hipError_t e = hipLaunchCooperativeKernel((const void*)k_all, dim3(GRID), dim3(256),
                                              args, 0, stream);
    if (e != hipSuccess) {
        // Fallback: 4-kernel chain (verified in round 1, no atomics/fences)
        float* scores = ws;                      // 20480
        int*   sel    = (int*)(ws + 20480);      // 640
        float* nllv   = ws + 21120;              // 9600
        float* corrv  = ws + 30720;              // 9600
        k_scores  <<<(NS * NUM_SLOT) / 4, 256, 0, stream>>>(out_f, scores);
        k_select  <<<1, 128, 0, stream>>>(scores, sel);
        k_main_fb <<<NQ / 4, 256, 0, stream>>>(out_f, sel, labels_q, nllv, corrv);
        k_finalize<<<1, 256, 0, stream>>>(nllv, corrv, att_loss, out);
    }
}

// Round 4
// 49.246 us; speedup vs baseline: 3.8750x; 3.8750x over previous
//
#include <hip/hip_runtime.h>

// Problem constants
#define B_       128
#define N_WAY    5
#define QUERY    15
#define NUM_SLOT 32
#define H_       256
#define NS       (B_ * N_WAY)            // 640 support samples
#define NQ       (B_ * N_WAY * QUERY)    // 9600 query samples
#define ROW      (NUM_SLOT * H_)         // 8192 floats per sample
#define SPB      (N_WAY * QUERY)         // 75 query samples per batch
#define RPB      (N_WAY * NUM_SLOT)      // 160 support rows per batch
#define NBLK_MAIN (NQ / 4)               // 2400 blocks, 4 samples (waves) each

__device__ __forceinline__ float wave_reduce(float v) {
    for (int m = 32; m > 0; m >>= 1) v += __shfl_xor(v, m, 64);
    return v;
}

// K1: one block per batch. Phase a: wave-reduce the batch's 160 contiguous
// support rows (mean over H) into LDS. Phase b: thread 0 greedy-selects 5
// slots from LDS (stable argsort semantics via strict >). Phase c: waves
// normalize the 5 selected rows (L2-hot) into proto.
__global__ __launch_bounds__(256)
void k_batch(const float* __restrict__ out_f, int* __restrict__ sel,
             float* __restrict__ proto) {
    int b = blockIdx.x;
    int t = threadIdx.x, wid = t >> 6, lane = t & 63;
    __shared__ float sc[RPB];
    __shared__ int ssel[N_WAY];

    // a) row means: row index in out_f = b*160 + (k*32 + j), contiguous
    const float* base = out_f + (size_t)b * RPB * H_;
    for (int i = wid; i < RPB; i += 4) {
        float4 v = ((const float4*)(base + (size_t)i * H_))[lane];
        float s = wave_reduce(v.x + v.y + v.z + v.w);
        if (lane == 0) sc[i] = s * (1.0f / H_);
    }
    __syncthreads();

    // b) greedy select (serial, tiny: 5 x 32 LDS reads)
    if (t == 0) {
        unsigned used = 0u;
        for (int j = 0; j < N_WAY; ++j) {
            float best = -INFINITY; int bi = 0;
            #pragma unroll
            for (int s = 0; s < NUM_SLOT; ++s) {
                bool ok = !((used >> s) & 1u);
                float v = sc[j * NUM_SLOT + s];
                if (ok && v > best) { best = v; bi = s; }  // strict > == stable pick
            }
            used |= 1u << bi;
            ssel[j] = bi;
        }
        #pragma unroll
        for (int j = 0; j < N_WAY; ++j) sel[b * N_WAY + j] = ssel[j];
    }
    __syncthreads();

    // c) normalize selected support rows -> proto (rows are L2-hot from phase a)
    for (int k = wid; k < N_WAY; k += 4) {
        int r = b * N_WAY + k;
        const float4* p = (const float4*)(base + ((size_t)k * NUM_SLOT + ssel[k]) * H_);
        float4 v = p[lane];
        float s2 = wave_reduce(v.x*v.x + v.y*v.y + v.z*v.z + v.w*v.w);
        float inv = 1.0f / fmaxf(sqrtf(s2), 1e-12f);
        ((float4*)(proto + (size_t)r * H_))[lane] =
            make_float4(v.x*inv, v.y*inv, v.z*inv, v.w*inv);
    }
}

// K2: per query-sample wave: 5x joint reduce (|q|^2, q.p, |p|^2) -> diffs,
// softmax-CE + argmin on lane 0; block writes ONE deterministic partial pair.
__global__ __launch_bounds__(256)
void k_main(const float* __restrict__ out_f, const int* __restrict__ sel,
            const float* __restrict__ proto, const int* __restrict__ labels_q,
            float* __restrict__ pn, float* __restrict__ pc) {
    int wid = threadIdx.x >> 6, lane = threadIdx.x & 63;
    int id = blockIdx.x * 4 + wid;                  // 0..9599 exact
    int b = id / SPB;
    const float* qrow = out_f + (size_t)(NS + id) * ROW;

    float diffs[N_WAY];
    #pragma unroll
    for (int k = 0; k < N_WAY; ++k) {
        int slot = sel[b * N_WAY + k];
        float4 qv = ((const float4*)(qrow + (size_t)slot * H_))[lane];
        float4 pv = ((const float4*)(proto + (size_t)(b * N_WAY + k) * H_))[lane];
        float s2 = qv.x*qv.x + qv.y*qv.y + qv.z*qv.z + qv.w*qv.w;
        float dt = qv.x*pv.x + qv.y*pv.y + qv.z*pv.z + qv.w*pv.w;
        float p2 = pv.x*pv.x + pv.y*pv.y + pv.z*pv.z + pv.w*pv.w;
        for (int m = 32; m > 0; m >>= 1) {
            s2 += __shfl_xor(s2, m, 64);
            dt += __shfl_xor(dt, m, 64);
            p2 += __shfl_xor(p2, m, 64);
        }
        float inv = 1.0f / fmaxf(sqrtf(s2), 1e-12f);
        diffs[k] = s2 * inv * inv - 2.0f * dt * inv + p2;
    }

    __shared__ float s_n[4], s_c[4];
    if (lane == 0) {
        int l = labels_q[id];                        // label == flat sample index
        float mn = diffs[0]; int am = 0;
        #pragma unroll
        for (int k = 1; k < N_WAY; ++k)
            if (diffs[k] < mn) { mn = diffs[k]; am = k; }   // first min == argmax logits
        float se = 0.0f;
        #pragma unroll
        for (int k = 0; k < N_WAY; ++k) se += expf(mn - diffs[k]);
        s_n[wid] = diffs[l] - mn + logf(se);
        s_c[wid] = (am == l) ? 1.0f : 0.0f;
    }
    __syncthreads();
    if (threadIdx.x == 0) {
        pn[blockIdx.x] = s_n[0] + s_n[1] + s_n[2] + s_n[3];
        pc[blockIdx.x] = s_c[0] + s_c[1] + s_c[2] + s_c[3];
    }
}

// K3: deterministic fixed-order reduction of 2400 partial pairs -> (loss, acc)
__global__ __launch_bounds__(256)
void k_finalize(const float* __restrict__ pn, const float* __restrict__ pc,
                const float* __restrict__ att_loss, float* __restrict__ out) {
    __shared__ float sa[256], sb[256];
    int t = threadIdx.x;
    float a = 0.0f, c = 0.0f;
    for (int i = t; i < NBLK_MAIN; i += 256) { a += pn[i]; c += pc[i]; }
    sa[t] = a; sb[t] = c;
    __syncthreads();
    for (int off = 128; off > 0; off >>= 1) {
        if (t < off) { sa[t] += sa[t + off]; sb[t] += sb[t + off]; }
        __syncthreads();
    }
    if (t == 0) {
        out[0] = sa[0] * (1.0f / NQ) + att_loss[0];   // LAMBDA = 1.0
        out[1] = sb[0] * (1.0f / NQ);
    }
}

extern "C" void kernel_launch(void* const* d_in, const int* in_sizes, int n_in,
                              void* d_out, int out_size, void* d_ws, size_t ws_size,
                              hipStream_t stream) {
    const float* out_f    = (const float*)d_in[0];
    // d_in[1] = labels_support (unused by reference)
    const int*   labels_q = (const int*)d_in[2];
    const float* att_loss = (const float*)d_in[3];
    // d_in[4] = mode (unused)
    float* out = (float*)d_out;

    // workspace layout (floats)
    float* ws    = (float*)d_ws;
    int*   sel   = (int*)ws;                 // 640
    float* proto = ws + 640;                 // 163840
    float* pn    = ws + 640 + 163840;        // 2400
    float* pc    = pn + NBLK_MAIN;           // 2400

    k_batch   <<<B_,        256, 0, stream>>>(out_f, sel, proto);
    k_main    <<<NBLK_MAIN, 256, 0, stream>>>(out_f, sel, proto, labels_q, pn, pc);
    k_finalize<<<1,         256, 0, stream>>>(pn, pc, att_loss, out);
}

// Round 5
// 34.222 us; speedup vs baseline: 5.5761x; 1.4390x over previous
//
#include <hip/hip_runtime.h>

// Problem constants
#define B_       128
#define N_WAY    5
#define QUERY    15
#define NUM_SLOT 32
#define H_       256
#define NS       (B_ * N_WAY)            // 640 support samples
#define NQ       (B_ * N_WAY * QUERY)    // 9600 query samples
#define ROW      (NUM_SLOT * H_)         // 8192 floats per sample
#define SPB      (N_WAY * QUERY)         // 75 query samples per batch
#define RPB      (N_WAY * NUM_SLOT)      // 160 support rows per batch
#define NBLK_MAIN (NQ / 4)               // 2400 blocks, 4 samples (waves) each

__device__ __forceinline__ float wave_reduce(float v) {
    for (int m = 32; m > 0; m >>= 1) v += __shfl_xor(v, m, 64);
    return v;
}

// K1: one block per batch, 16 waves. Phase a: wave-reduce the batch's 160
// contiguous support rows (mean over H) into LDS, 2-deep ILP. Phase b:
// thread 0 greedy-selects 5 slots (stable argsort semantics via strict >).
// Phase c: 5 waves normalize the selected rows (L2-hot) into proto.
__global__ __launch_bounds__(1024)
void k_batch(const float* __restrict__ out_f, int* __restrict__ sel,
             float* __restrict__ proto) {
    int b = blockIdx.x;
    int t = threadIdx.x, wid = t >> 6, lane = t & 63;
    __shared__ float sc[RPB];
    __shared__ int ssel[N_WAY];

    // a) row means: rows are contiguous: out_f[b*160 + i][:]
    const float* base = out_f + (size_t)b * RPB * H_;
    // 160 rows / 16 waves = 10 rows per wave; process 2 at a time for ILP
    for (int i = wid; i < RPB; i += 32) {
        float4 v0 = ((const float4*)(base + (size_t)i * H_))[lane];
        float4 v1 = ((const float4*)(base + (size_t)(i + 16) * H_))[lane];
        float s0 = wave_reduce(v0.x + v0.y + v0.z + v0.w);
        float s1 = wave_reduce(v1.x + v1.y + v1.z + v1.w);
        if (lane == 0) { sc[i] = s0 * (1.0f / H_); sc[i + 16] = s1 * (1.0f / H_); }
    }
    __syncthreads();

    // b) greedy select (serial, tiny: 5 x 32 LDS reads)
    if (t == 0) {
        unsigned used = 0u;
        for (int j = 0; j < N_WAY; ++j) {
            float best = -INFINITY; int bi = 0;
            #pragma unroll
            for (int s = 0; s < NUM_SLOT; ++s) {
                bool ok = !((used >> s) & 1u);
                float v = sc[j * NUM_SLOT + s];
                if (ok && v > best) { best = v; bi = s; }  // strict > == stable pick
            }
            used |= 1u << bi;
            ssel[j] = bi;
        }
        #pragma unroll
        for (int j = 0; j < N_WAY; ++j) sel[b * N_WAY + j] = ssel[j];
    }
    __syncthreads();

    // c) normalize selected support rows -> proto (rows are L2-hot from phase a)
    if (wid < N_WAY) {
        int k = wid;
        int r = b * N_WAY + k;
        const float4* p = (const float4*)(base + ((size_t)k * NUM_SLOT + ssel[k]) * H_);
        float4 v = p[lane];
        float s2 = wave_reduce(v.x*v.x + v.y*v.y + v.z*v.z + v.w*v.w);
        float inv = 1.0f / fmaxf(sqrtf(s2), 1e-12f);
        ((float4*)(proto + (size_t)r * H_))[lane] =
            make_float4(v.x*inv, v.y*inv, v.z*inv, v.w*inv);
    }
}

// K2: per query-sample wave: 5x joint reduce (|q|^2, q.p, |p|^2) -> diffs,
// softmax-CE + argmin on lane 0; block writes ONE deterministic float2 partial.
__global__ __launch_bounds__(256)
void k_main(const float* __restrict__ out_f, const int* __restrict__ sel,
            const float* __restrict__ proto, const int* __restrict__ labels_q,
            float2* __restrict__ part) {
    int wid = threadIdx.x >> 6, lane = threadIdx.x & 63;
    int id = blockIdx.x * 4 + wid;                  // 0..9599 exact
    int b = id / SPB;
    const float* qrow = out_f + (size_t)(NS + id) * ROW;

    float diffs[N_WAY];
    #pragma unroll
    for (int k = 0; k < N_WAY; ++k) {
        int slot = sel[b * N_WAY + k];
        float4 qv = ((const float4*)(qrow + (size_t)slot * H_))[lane];
        float4 pv = ((const float4*)(proto + (size_t)(b * N_WAY + k) * H_))[lane];
        float s2 = qv.x*qv.x + qv.y*qv.y + qv.z*qv.z + qv.w*qv.w;
        float dt = qv.x*pv.x + qv.y*pv.y + qv.z*pv.z + qv.w*pv.w;
        float p2 = pv.x*pv.x + pv.y*pv.y + pv.z*pv.z + pv.w*pv.w;
        for (int m = 32; m > 0; m >>= 1) {
            s2 += __shfl_xor(s2, m, 64);
            dt += __shfl_xor(dt, m, 64);
            p2 += __shfl_xor(p2, m, 64);
        }
        float inv = 1.0f / fmaxf(sqrtf(s2), 1e-12f);
        diffs[k] = s2 * inv * inv - 2.0f * dt * inv + p2;
    }

    __shared__ float s_n[4], s_c[4];
    if (lane == 0) {
        int l = labels_q[id];                        // label == flat sample index
        float mn = diffs[0]; int am = 0;
        #pragma unroll
        for (int k = 1; k < N_WAY; ++k)
            if (diffs[k] < mn) { mn = diffs[k]; am = k; }   // first min == argmax logits
        float se = 0.0f;
        #pragma unroll
        for (int k = 0; k < N_WAY; ++k) se += expf(mn - diffs[k]);
        s_n[wid] = diffs[l] - mn + logf(se);
        s_c[wid] = (am == l) ? 1.0f : 0.0f;
    }
    __syncthreads();
    if (threadIdx.x == 0)
        part[blockIdx.x] = make_float2(s_n[0] + s_n[1] + s_n[2] + s_n[3],
                                       s_c[0] + s_c[1] + s_c[2] + s_c[3]);
}

// K3: deterministic fixed-order reduction of 2400 float2 partials -> (loss, acc)
__global__ __launch_bounds__(256)
void k_finalize(const float2* __restrict__ part, const float* __restrict__ att_loss,
                float* __restrict__ out) {
    __shared__ float sa[4], sb[4];
    int t = threadIdx.x, wid = t >> 6, lane = t & 63;
    float a = 0.0f, c = 0.0f;
    for (int i = t; i < NBLK_MAIN; i += 256) { float2 p = part[i]; a += p.x; c += p.y; }
    a = wave_reduce(a); c = wave_reduce(c);
    if (lane == 0) { sa[wid] = a; sb[wid] = c; }
    __syncthreads();
    if (t == 0) {
        float sn_ = sa[0] + sa[1] + sa[2] + sa[3];
        float sc_ = sb[0] + sb[1] + sb[2] + sb[3];
        out[0] = sn_ * (1.0f / NQ) + att_loss[0];   // LAMBDA = 1.0
        out[1] = sc_ * (1.0f / NQ);
    }
}

extern "C" void kernel_launch(void* const* d_in, const int* in_sizes, int n_in,
                              void* d_out, int out_size, void* d_ws, size_t ws_size,
                              hipStream_t stream) {
    const float* out_f    = (const float*)d_in[0];
    // d_in[1] = labels_support (unused by reference)
    const int*   labels_q = (const int*)d_in[2];
    const float* att_loss = (const float*)d_in[3];
    // d_in[4] = mode (unused)
    float* out = (float*)d_out;

    // workspace layout (floats)
    float*  ws    = (float*)d_ws;
    int*    sel   = (int*)ws;                 // 640
    float*  proto = ws + 640;                 // 163840
    float2* part  = (float2*)(ws + 640 + 163840);   // 2400 float2

    k_batch   <<<B_,        1024, 0, stream>>>(out_f, sel, proto);
    k_main    <<<NBLK_MAIN, 256,  0, stream>>>(out_f, sel, proto, labels_q, part);
    k_finalize<<<1,         256,  0, stream>>>(part, att_loss, out);
}

// Round 6
// 30.075 us; speedup vs baseline: 6.3450x; 1.1379x over previous
//
#include <hip/hip_runtime.h>

// Problem constants
#define B_       128
#define N_WAY    5
#define QUERY    15
#define NUM_SLOT 32
#define H_       256
#define NS       (B_ * N_WAY)            // 640 support samples
#define NQ       (B_ * N_WAY * QUERY)    // 9600 query samples
#define ROW      (NUM_SLOT * H_)         // 8192 floats per sample
#define SPB      (N_WAY * QUERY)         // 75 query samples per batch
#define RPB      (N_WAY * NUM_SLOT)      // 160 support rows per batch
#define NBLK     (2 * B_)                // 256 blocks, 2 per batch

__device__ __forceinline__ float wave_reduce(float v) {
    for (int m = 32; m > 0; m >>= 1) v += __shfl_xor(v, m, 64);
    return v;
}

// K1: 2 blocks per batch, 16 waves each (full chip).
//  a) wave-reduce the batch's 160 contiguous support rows -> LDS scores
//     (pair-redundant read; second copy is L3-hot)
//  b) thread 0 greedy-selects 5 slots (stable argsort semantics, strict >)
//  c) waves 0-4 normalize the selected rows into LDS protos (+ exact p2)
//  d) each wave handles its share of the block's 38/37 query samples:
//     preload 5 qv float4, joint s2/dt shuffle reduce (same tree/bits as R5),
//     softmax-CE + argmin on lane 0, accumulate per-wave partials
//  e) one deterministic float2 partial per block
__global__ __launch_bounds__(1024)
void k_fused(const float* __restrict__ out_f, const int* __restrict__ labels_q,
             float2* __restrict__ part) {
    int blk = blockIdx.x, b = blk >> 1, half = blk & 1;
    int t = threadIdx.x, wid = t >> 6, lane = t & 63;

    __shared__ float sc[RPB];
    __shared__ int ssel[N_WAY];
    __shared__ __align__(16) float pl[N_WAY][H_];   // normalized protos (5 KB)
    __shared__ float p2s[N_WAY];
    __shared__ float s_n[16], s_c[16];

    // a) row means: rows contiguous at out_f[b*160 + i][:]
    const float* base = out_f + (size_t)b * RPB * H_;
    for (int i = wid; i < RPB; i += 32) {           // 16 waves x (2 rows x 5 iters)
        float4 v0 = ((const float4*)(base + (size_t)i * H_))[lane];
        float4 v1 = ((const float4*)(base + (size_t)(i + 16) * H_))[lane];
        float s0 = wave_reduce(v0.x + v0.y + v0.z + v0.w);
        float s1 = wave_reduce(v1.x + v1.y + v1.z + v1.w);
        if (lane == 0) { sc[i] = s0 * (1.0f / H_); sc[i + 16] = s1 * (1.0f / H_); }
    }
    __syncthreads();

    // b) greedy select
    if (t == 0) {
        unsigned used = 0u;
        for (int j = 0; j < N_WAY; ++j) {
            float best = -INFINITY; int bi = 0;
            #pragma unroll
            for (int s = 0; s < NUM_SLOT; ++s) {
                bool ok = !((used >> s) & 1u);
                float v = sc[j * NUM_SLOT + s];
                if (ok && v > best) { best = v; bi = s; }  // strict > == stable pick
            }
            used |= 1u << bi;
            ssel[j] = bi;
        }
    }
    __syncthreads();

    // c) normalize selected rows -> LDS protos; p2 via same reduce tree as before
    if (wid < N_WAY) {
        int k = wid;
        float4 v = ((const float4*)(base + ((size_t)k * NUM_SLOT + ssel[k]) * H_))[lane];
        float s2 = wave_reduce(v.x*v.x + v.y*v.y + v.z*v.z + v.w*v.w);
        float inv = 1.0f / fmaxf(sqrtf(s2), 1e-12f);
        float4 nv = make_float4(v.x*inv, v.y*inv, v.z*inv, v.w*inv);
        *(float4*)&pl[k][lane * 4] = nv;
        float p2 = wave_reduce(nv.x*nv.x + nv.y*nv.y + nv.z*nv.z + nv.w*nv.w);
        if (lane == 0) p2s[k] = p2;
    }
    __syncthreads();

    // d) query samples: half 0 -> [0,38), half 1 -> [38,75)
    int sBeg = half ? 38 : 0;
    int sEnd = half ? SPB : 38;
    float accn = 0.0f, accc = 0.0f;
    for (int s = sBeg + wid; s < sEnd; s += 16) {
        int id = b * SPB + s;
        const float* qrow = out_f + (size_t)(NS + id) * ROW;
        float4 qv[N_WAY];
        #pragma unroll
        for (int k = 0; k < N_WAY; ++k)             // issue all 5 loads up front
            qv[k] = ((const float4*)(qrow + (size_t)ssel[k] * H_))[lane];
        float diffs[N_WAY];
        #pragma unroll
        for (int k = 0; k < N_WAY; ++k) {
            float4 pv = *(const float4*)&pl[k][lane * 4];
            float s2 = qv[k].x*qv[k].x + qv[k].y*qv[k].y + qv[k].z*qv[k].z + qv[k].w*qv[k].w;
            float dt = qv[k].x*pv.x + qv[k].y*pv.y + qv[k].z*pv.z + qv[k].w*pv.w;
            for (int m = 32; m > 0; m >>= 1) {
                s2 += __shfl_xor(s2, m, 64);
                dt += __shfl_xor(dt, m, 64);
            }
            float inv = 1.0f / fmaxf(sqrtf(s2), 1e-12f);
            diffs[k] = s2 * inv * inv - 2.0f * dt * inv + p2s[k];
        }
        if (lane == 0) {
            int l = labels_q[id];                   // label index == flat sample index
            float mn = diffs[0]; int am = 0;
            #pragma unroll
            for (int k = 1; k < N_WAY; ++k)
                if (diffs[k] < mn) { mn = diffs[k]; am = k; }  // first min == argmax logits
            float se = 0.0f;
            #pragma unroll
            for (int k = 0; k < N_WAY; ++k) se += expf(mn - diffs[k]);
            accn += diffs[l] - mn + logf(se);
            accc += (am == l) ? 1.0f : 0.0f;
        }
    }
    if (lane == 0) { s_n[wid] = accn; s_c[wid] = accc; }
    __syncthreads();

    // e) deterministic per-block partial
    if (t == 0) {
        float a = 0.0f, c = 0.0f;
        #pragma unroll
        for (int i = 0; i < 16; ++i) { a += s_n[i]; c += s_c[i]; }
        part[blk] = make_float2(a, c);
    }
}

// K2: deterministic fixed-order reduction of 256 float2 partials -> (loss, acc)
__global__ __launch_bounds__(256)
void k_finalize(const float2* __restrict__ part, const float* __restrict__ att_loss,
                float* __restrict__ out) {
    __shared__ float sa[4], sb[4];
    int t = threadIdx.x, wid = t >> 6, lane = t & 63;
    float2 p = part[t];                             // exactly 256 partials
    float a = wave_reduce(p.x);
    float c = wave_reduce(p.y);
    if (lane == 0) { sa[wid] = a; sb[wid] = c; }
    __syncthreads();
    if (t == 0) {
        float sn_ = sa[0] + sa[1] + sa[2] + sa[3];
        float sc_ = sb[0] + sb[1] + sb[2] + sb[3];
        out[0] = sn_ * (1.0f / NQ) + att_loss[0];   // LAMBDA = 1.0
        out[1] = sc_ * (1.0f / NQ);
    }
}

extern "C" void kernel_launch(void* const* d_in, const int* in_sizes, int n_in,
                              void* d_out, int out_size, void* d_ws, size_t ws_size,
                              hipStream_t stream) {
    const float* out_f    = (const float*)d_in[0];
    // d_in[1] = labels_support (unused by reference)
    const int*   labels_q = (const int*)d_in[2];
    const float* att_loss = (const float*)d_in[3];
    // d_in[4] = mode (unused)
    float* out = (float*)d_out;

    float2* part = (float2*)d_ws;                   // 256 float2

    k_fused   <<<NBLK, 1024, 0, stream>>>(out_f, labels_q, part);
    k_finalize<<<1,    256,  0, stream>>>(part, att_loss, out);
}